// Round 1
// baseline (76.167 us; speedup 1.0000x reference)
//
#include <hip/hip_runtime.h>

#define NG 256                 // 4 batches * 4 sem * 16 classes
#define AGG_FLOATS (10 * NG)   // count, msum, esum[8]  (SoA: [field][g])
#define PAR_FLOATS (13 * NG)   // cent[8], cent2, inv_denom, bce_scale, sigma, smooth_scale

__global__ void k_zero(float* __restrict__ agg, float* __restrict__ out) {
    int t = blockIdx.x * blockDim.x + threadIdx.x;
    if (t < AGG_FLOATS) agg[t] = 0.0f;
    if (t == 0) out[0] = 0.0f;
}

__global__ void k_agg(const float* __restrict__ emb, const float* __restrict__ marg,
                      const int* __restrict__ slab, const int* __restrict__ clab,
                      const int* __restrict__ bidx, float* __restrict__ agg, int n) {
    __shared__ float sa[AGG_FLOATS];
    for (int t = threadIdx.x; t < AGG_FLOATS; t += blockDim.x) sa[t] = 0.0f;
    __syncthreads();
    int stride = gridDim.x * blockDim.x;
    for (int i = blockIdx.x * blockDim.x + threadIdx.x; i < n; i += stride) {
        int s = slab[i];
        if (s >= 4) continue;                     // s==4 points excluded everywhere
        int g = ((bidx[i] * 4 + s) << 4) | clab[i];
        const float4* e4 = (const float4*)(emb + (size_t)i * 8);
        float4 e0 = e4[0], e1 = e4[1];
        atomicAdd(&sa[g],        1.0f);
        atomicAdd(&sa[NG + g],   marg[i]);
        atomicAdd(&sa[2*NG + g], e0.x);
        atomicAdd(&sa[3*NG + g], e0.y);
        atomicAdd(&sa[4*NG + g], e0.z);
        atomicAdd(&sa[5*NG + g], e0.w);
        atomicAdd(&sa[6*NG + g], e1.x);
        atomicAdd(&sa[7*NG + g], e1.y);
        atomicAdd(&sa[8*NG + g], e1.z);
        atomicAdd(&sa[9*NG + g], e1.w);
    }
    __syncthreads();
    for (int t = threadIdx.x; t < AGG_FLOATS; t += blockDim.x) {
        float v = sa[t];
        if (v != 0.0f) atomicAdd(&agg[t], v);
    }
}

__global__ void k_final(const float* __restrict__ agg, float* __restrict__ par) {
    int g = threadIdx.x;   // 256 threads, 1 block; 16 consecutive threads = one (b,s)
    float count = agg[g];
    float msum  = agg[NG + g];
    bool present = count > 0.0f;
    float cnt = present ? count : 1.0f;
    float nsub = count, ncl = present ? 1.0f : 0.0f;
    #pragma unroll
    for (int m = 1; m < 16; m <<= 1) {           // xor of bits 0-3 stays in 16-lane group
        nsub += __shfl_xor(nsub, m);
        ncl  += __shfl_xor(ncl, m);
    }
    nsub = fmaxf(nsub, 1.0f);
    ncl  = fmaxf(ncl, 1.0f);
    float sigma = msum / cnt;
    float c2 = 0.0f;
    #pragma unroll
    for (int d = 0; d < 8; ++d) {
        float cd = agg[(2 + d) * NG + g] / cnt;
        par[d * NG + g] = cd;
        c2 += cd * cd;
    }
    par[8*NG + g]  = c2;
    par[9*NG + g]  = 1.0f / (2.0f * sigma * sigma + 1e-8f);
    par[10*NG + g] = present ? 1.0f / (16.0f * nsub * ncl) : 0.0f;
    par[11*NG + g] = sigma;
    par[12*NG + g] = 1.0f / (16.0f * ncl);
}

__global__ void k_main(const float* __restrict__ emb, const float* __restrict__ marg,
                       const int* __restrict__ slab, const int* __restrict__ clab,
                       const int* __restrict__ bidx, const float* __restrict__ par,
                       float* __restrict__ out, int n) {
    __shared__ float sp[PAR_FLOATS];
    __shared__ float wsum[4];
    for (int t = threadIdx.x; t < PAR_FLOATS; t += blockDim.x) sp[t] = par[t];
    __syncthreads();
    float acc = 0.0f;
    int stride = gridDim.x * blockDim.x;
    for (int i = blockIdx.x * blockDim.x + threadIdx.x; i < n; i += stride) {
        int s = slab[i];
        if (s >= 4) continue;
        int b = bidx[i], cl = clab[i];
        int base = (b * 4 + s) << 4;
        const float4* e4 = (const float4*)(emb + (size_t)i * 8);
        float4 ea = e4[0], eb = e4[1];
        float e[8] = {ea.x, ea.y, ea.z, ea.w, eb.x, eb.y, eb.z, eb.w};
        float e2 = 0.0f;
        #pragma unroll
        for (int d = 0; d < 8; ++d) e2 += e[d] * e[d];
        float m = marg[i];
        float lsum = 0.0f;
        #pragma unroll
        for (int c = 0; c < 16; ++c) {
            int g = base + c;
            float dot = 0.0f;
            #pragma unroll
            for (int d = 0; d < 8; ++d) dot += sp[d * NG + g] * e[d];
            float dist = e2 + sp[8*NG + g] - 2.0f * dot;
            float p  = __expf(-dist * sp[9*NG + g]);
            float pc = fminf(fmaxf(p, 1e-6f), 1.0f - 1e-6f);
            float x  = __logf(pc) - __logf(1.0f - pc);
            float t  = (c == cl) ? 1.0f : 0.0f;
            float bce = fmaxf(x, 0.0f) - x * t + __logf(1.0f + __expf(-fabsf(x)));
            lsum += bce * sp[10*NG + g];
        }
        float sg = sp[11*NG + base + cl];
        float dm = m - sg;
        acc += lsum + dm * dm * sp[12*NG + base + cl];
    }
    #pragma unroll
    for (int off = 32; off >= 1; off >>= 1) acc += __shfl_down(acc, off);
    int wid = threadIdx.x >> 6, lane = threadIdx.x & 63;
    if (lane == 0) wsum[wid] = acc;
    __syncthreads();
    if (threadIdx.x == 0) {
        float t = 0.0f;
        int nw = blockDim.x >> 6;
        for (int w = 0; w < nw; ++w) t += wsum[w];
        atomicAdd(out, t);
    }
}

extern "C" void kernel_launch(void* const* d_in, const int* in_sizes, int n_in,
                              void* d_out, int out_size, void* d_ws, size_t ws_size,
                              hipStream_t stream) {
    const float* emb  = (const float*)d_in[0];
    const float* marg = (const float*)d_in[1];
    const int*   slab = (const int*)d_in[2];
    const int*   clab = (const int*)d_in[3];
    const int*   bidx = (const int*)d_in[4];
    float* out = (float*)d_out;
    int n = in_sizes[2];

    float* agg = (float*)d_ws;
    float* par = agg + AGG_FLOATS;

    k_zero <<<(AGG_FLOATS + 255) / 256, 256, 0, stream>>>(agg, out);
    k_agg  <<<512, 256, 0, stream>>>(emb, marg, slab, clab, bidx, agg, n);
    k_final<<<1, 256, 0, stream>>>(agg, par);
    k_main <<<1024, 256, 0, stream>>>(emb, marg, slab, clab, bidx, par, out, n);
}